// Round 1
// 316.689 us; speedup vs baseline: 1.0227x; 1.0227x over previous
//
#include <hip/hip_runtime.h>
#include <cstdint>
#include <cstddef>

// ---------------------------------------------------------------------------
// Net_25950192402497: 2-layer MLP-message GNN + link-prediction head.
// Identity: segment_sum(concat(x_i,x_j,ef)@W + b) over dst
//   = deg*(h@Wi + b) + (gather-sum h[src])@Wj + (gather-sum ef)@We
// R13: gather restructured for MLP (latency-bound per counters: 0 MFMA,
// 19% VALU, 34% HBM, 67% occ): 16 lanes/node x uint4 (4 nodes/wave),
// unroll-8 -> 32 outstanding 256B rows/wave (2x prev); elist read once as
// a 16-wide vector load + __shfl broadcast (kills the serial elist->row
// dependent chain); ef accumulation fused into the same edge loop (drops
// the second elist pass). GEMM left at R9/R12 form.
// ---------------------------------------------------------------------------

typedef __attribute__((ext_vector_type(8))) short short8;
typedef __attribute__((ext_vector_type(4))) float float4v;

__device__ __forceinline__ ushort f2b(float f) {
    uint u = __float_as_uint(f);
    u = u + 0x7fff + ((u >> 16) & 1);          // round-to-nearest-even
    return (ushort)(u >> 16);
}
__device__ __forceinline__ float b2f(ushort h) {
    return __uint_as_float(((uint)h) << 16);
}
__device__ __forceinline__ uint pack2(float a, float b) {
    return (uint)f2b(a) | ((uint)f2b(b) << 16);
}

#define F_MSG     1   // X = [deg*A | B | EF | 0] in k-space (Kp=320)
#define F_RELU    2
#define F_DEGBIAS 4
#define F_OUTB    8   // write bf16 output [row][128]
#define F_IN32    16  // A is fp32, convert during staging
#define F_HEAD    32  // no row output; emit z[row] = {za0,za1,zb0,zb1}

#define XS_STRIDE 72  // 144 B rows: max 2-way bank aliasing (free), 16B aligned

// MFMA GEMM (R9 form): act( X[r,0:Kp] @ W[Kp,128] + bias ).
// Wt bf16 transposed [n=128][Kp], zero-padded; Kp % 64 == 0.
// Block: 128 rows x 128 cols, 4 waves; wave w owns rows w*32..w*32+31
// (2 m-subtiles of 16), all 128 cols as 8 col-tiles. acc = 2x8 float4.
__launch_bounds__(256, 2)
__global__ void gemm_mfma(const ushort* __restrict__ A, const ushort* __restrict__ B,
                          const ushort* __restrict__ EF, const float* __restrict__ A32,
                          const float* __restrict__ DEG, const ushort* __restrict__ Wt,
                          const float* __restrict__ bias, ushort* __restrict__ outB,
                          const float* __restrict__ lpW, float* __restrict__ z,
                          int M, int Kp, int flags)
{
    __shared__ ushort xs[128 * XS_STRIDE];   // 18 KB
    __shared__ ushort ws[128 * XS_STRIDE];   // 18 KB
    const int tid  = threadIdx.x;
    const int lane = tid & 63;
    const int wave = tid >> 6;
    const int row0 = blockIdx.x << 7;

    float4v acc[2][8];
#pragma unroll
    for (int m = 0; m < 2; ++m)
#pragma unroll
        for (int t = 0; t < 8; ++t) acc[m][t] = (float4v){0.f, 0.f, 0.f, 0.f};

    const int arow0 = (wave << 5) + (lane & 15);
    const int koff  = (lane >> 4) << 3;
    const int bcol  = lane & 15;

    for (int kt = 0; kt < Kp; kt += 64) {
        __syncthreads();
        for (int idx = tid; idx < 128 * 8; idx += 256) {
            const int n = idx >> 3;
            const int g = idx & 7;
            const uint4 v = *(const uint4*)&Wt[(size_t)n * Kp + kt + (g << 3)];
            *(uint4*)&ws[n * XS_STRIDE + (g << 3)] = v;
        }
        if (flags & F_MSG) {
            for (int idx = tid; idx < 128 * 8; idx += 256) {
                const int r  = idx >> 3;
                const int g  = idx & 7;
                const int gr = row0 + r;
                const int kk = kt + (g << 3);
                uint4 v = make_uint4(0, 0, 0, 0);
                if (gr < M) {
                    if (kk < 128) {                       // deg * A
                        uint4 a = *(const uint4*)&A[((size_t)gr << 7) + kk];
                        const float d = DEG[gr];
                        uint* p = (uint*)&a;
#pragma unroll
                        for (int q = 0; q < 4; ++q)
                            p[q] = pack2(b2f((ushort)(p[q] & 0xffff)) * d,
                                         b2f((ushort)(p[q] >> 16)) * d);
                        v = a;
                    } else if (kk < 256) {                // B
                        v = *(const uint4*)&B[((size_t)gr << 7) + kk - 128];
                    } else if (kk < 272) {                // EF
                        v = *(const uint4*)&EF[((size_t)gr << 4) + kk - 256];
                    }
                }
                *(uint4*)&xs[r * XS_STRIDE + (g << 3)] = v;
            }
        } else if (flags & F_IN32) {
            for (int idx = tid; idx < 128 * 8; idx += 256) {
                const int r  = idx >> 3;
                const int g  = idx & 7;
                const int gr = row0 + r;
                uint4 v = make_uint4(0, 0, 0, 0);
                if (gr < M) {
                    const float4 f0 = *(const float4*)&A32[((size_t)gr << 7) + kt + (g << 3)];
                    const float4 f1 = *(const float4*)&A32[((size_t)gr << 7) + kt + (g << 3) + 4];
                    v.x = pack2(f0.x, f0.y); v.y = pack2(f0.z, f0.w);
                    v.z = pack2(f1.x, f1.y); v.w = pack2(f1.z, f1.w);
                }
                *(uint4*)&xs[r * XS_STRIDE + (g << 3)] = v;
            }
        } else {
            for (int idx = tid; idx < 128 * 8; idx += 256) {
                const int r  = idx >> 3;
                const int g  = idx & 7;
                const int gr = row0 + r;
                uint4 v = make_uint4(0, 0, 0, 0);
                if (gr < M) v = *(const uint4*)&A[((size_t)gr << 7) + kt + (g << 3)];
                *(uint4*)&xs[r * XS_STRIDE + (g << 3)] = v;
            }
        }
        __syncthreads();
#pragma unroll
        for (int s = 0; s < 64; s += 32) {
            const short8 a0 = *(const short8*)&xs[arow0 * XS_STRIDE + s + koff];
            const short8 a1 = *(const short8*)&xs[(arow0 + 16) * XS_STRIDE + s + koff];
#pragma unroll
            for (int t = 0; t < 8; ++t) {
                const short8 bf = *(const short8*)&ws[((t << 4) + bcol) * XS_STRIDE + s + koff];
                acc[0][t] = __builtin_amdgcn_mfma_f32_16x16x32_bf16(a0, bf, acc[0][t], 0, 0, 0);
                acc[1][t] = __builtin_amdgcn_mfma_f32_16x16x32_bf16(a1, bf, acc[1][t], 0, 0, 0);
            }
        }
    }

    // ---- epilogue: C/D layout col=lane&15, row=(lane>>4)*4+reg ----
    float bcv[8];
#pragma unroll
    for (int t = 0; t < 8; ++t) bcv[t] = bias[(t << 4) + bcol];

    if (flags & F_HEAD) {
        const float2* lw = (const float2*)lpW;
        float2 wa[8], wb[8];
#pragma unroll
        for (int t = 0; t < 8; ++t) {
            const int col = (t << 4) + bcol;
            wa[t] = lw[col];
            wb[t] = lw[128 + col];
        }
#pragma unroll
        for (int m = 0; m < 2; ++m) {
            const int rbase = row0 + (wave << 5) + (m << 4) + ((lane >> 4) << 2);
#pragma unroll
            for (int r = 0; r < 4; ++r) {
                const int row = rbase + r;
                const float d = (row < M) ? DEG[row] : 0.f;
                float za0 = 0.f, za1 = 0.f, zb0 = 0.f, zb1 = 0.f;
#pragma unroll
                for (int t = 0; t < 8; ++t) {
                    const float v = acc[m][t][r] + d * bcv[t];
                    za0 += v * wa[t].x; za1 += v * wa[t].y;
                    zb0 += v * wb[t].x; zb1 += v * wb[t].y;
                }
#pragma unroll
                for (int mk = 8; mk > 0; mk >>= 1) {
                    za0 += __shfl_xor(za0, mk);
                    za1 += __shfl_xor(za1, mk);
                    zb0 += __shfl_xor(zb0, mk);
                    zb1 += __shfl_xor(zb1, mk);
                }
                if (bcol == 0 && row < M)
                    *(float4*)&z[(size_t)row * 4] = make_float4(za0, za1, zb0, zb1);
            }
        }
    } else {
#pragma unroll
        for (int m = 0; m < 2; ++m) {
            const int rbase = row0 + (wave << 5) + (m << 4) + ((lane >> 4) << 2);
#pragma unroll
            for (int t = 0; t < 8; ++t) {
                const int col = (t << 4) + bcol;
#pragma unroll
                for (int r = 0; r < 4; ++r) {
                    const int row = rbase + r;
                    if (row >= M) continue;
                    float v = acc[m][t][r];
                    v += (flags & F_DEGBIAS) ? DEG[row] * bcv[t] : bcv[t];
                    if (flags & F_RELU) v = fmaxf(v, 0.f);
                    outB[((size_t)row << 7) + col] = f2b(v);
                }
            }
        }
    }
}

// ---- prep: zero counts + convert all 4 weight matrices (bf16, T, padded) ----
__launch_bounds__(256)
__global__ void prep(const float* __restrict__ c1pW, const float* __restrict__ c2pW,
                     const float* __restrict__ c1mW, const float* __restrict__ c2mW,
                     ushort* __restrict__ wtp1, ushort* __restrict__ wtp2,
                     ushort* __restrict__ wtm1, ushort* __restrict__ wtm2,
                     int* __restrict__ counts, int N)
{
    const int gtid = blockIdx.x * 256 + threadIdx.x;
    const int gstr = gridDim.x * 256;
    for (int i = gtid; i < N; i += gstr) counts[i] = 0;
    for (int idx = gtid; idx < 128 * 128; idx += gstr) {
        const int n = idx >> 7, k = idx & 127;
        wtp1[idx] = f2b(c1pW[(size_t)k * 128 + n]);
        wtp2[idx] = f2b(c2pW[(size_t)k * 128 + n]);
    }
    for (int idx = gtid; idx < 128 * 320; idx += gstr) {
        const int n = idx / 320, k = idx - n * 320;
        wtm1[idx] = (k < 272) ? f2b(c1mW[(size_t)k * 128 + n]) : (ushort)0;
        wtm2[idx] = (k < 272) ? f2b(c2mW[(size_t)k * 128 + n]) : (ushort)0;
    }
}

__launch_bounds__(256)
__global__ void hist_kernel(const int* __restrict__ ei, int* __restrict__ counts, int E)
{
    const int e = blockIdx.x * 256 + threadIdx.x;
    if (e < E) atomicAdd(&counts[ei[E + e]], 1);
}

__launch_bounds__(256)
__global__ void scan_phase1(const int* __restrict__ counts, int* __restrict__ rowstart,
                            int* __restrict__ blocksums, int N)
{
    __shared__ int sdata[256];
    const int t = threadIdx.x;
    const int i = blockIdx.x * 256 + t;
    const int v = (i < N) ? counts[i] : 0;
    sdata[t] = v;
    __syncthreads();
    for (int off = 1; off < 256; off <<= 1) {
        const int add = (t >= off) ? sdata[t - off] : 0;
        __syncthreads();
        sdata[t] += add;
        __syncthreads();
    }
    if (i < N) rowstart[i] = sdata[t] - v;
    if (t == 255) blocksums[blockIdx.x] = sdata[255];
}

// merged scan phases 2+3: block vb sums blocksums[0..vb) itself (~196 blocks)
__launch_bounds__(256)
__global__ void scan_phase23(const int* __restrict__ counts, const int* __restrict__ bs,
                             int* __restrict__ rowstart, int* __restrict__ cursor,
                             float* __restrict__ degf, int N, int E)
{
    __shared__ int sdata[256];
    const int t = threadIdx.x;
    const int vb = blockIdx.x;
    int part = 0;
    for (int j = t; j < vb; j += 256) part += bs[j];
    sdata[t] = part;
    __syncthreads();
    for (int s = 128; s > 0; s >>= 1) {
        if (t < s) sdata[t] += sdata[t + s];
        __syncthreads();
    }
    const int off = sdata[0];
    const int i = vb * 256 + t;
    if (i < N) {
        const int rs = rowstart[i] + off;
        rowstart[i] = rs;
        cursor[i]   = rs;
        degf[i]     = (float)counts[i];
    }
    if (vb == 0 && t == 0) rowstart[N] = E;
}

__launch_bounds__(256)
__global__ void build_elist(const int* __restrict__ ei, int* __restrict__ cursor,
                            int2* __restrict__ elist, int E)
{
    const int e = blockIdx.x * 256 + threadIdx.x;
    if (e >= E) return;
    const int d = ei[E + e];
    const int pos = atomicAdd(&cursor[d], 1);
    elist[pos] = make_int2(ei[e], e);
}

// gather (R13): 16 lanes per node (4 nodes/wave), uint4 (16B) per lane per
// edge, unroll-8 -> 32 outstanding 256B row loads per wave (2x R12).
// elist is read ONCE per 16-edge chunk as a lane-parallel int2 vector load;
// per-edge src / edge-id broadcast via __shfl within the 16-lane group
// (removes the serial elist->row dependent chain). ef accumulation is fused
// into the same loop (one elist pass total; 8 extra independent 4B loads
// per batch join the MLP pool).
__launch_bounds__(256)
__global__ void gather(const int2* __restrict__ elist, const int* __restrict__ rowstart,
                       const ushort* __restrict__ h, ushort* __restrict__ agg,
                       const float* __restrict__ ef, ushort* __restrict__ aggef,
                       int N, int doEf)
{
    const int tid = threadIdx.x;
    const int grp = tid >> 4;          // 0..15 (node group within block)
    const int l   = tid & 15;          // lane within group
    const int nvb = (N + 15) / 16;     // 16 nodes per block
    for (int vb = blockIdx.x; vb < nvb; vb += gridDim.x) {
        const int node = vb * 16 + grp;
        if (node >= N) continue;
        const int beg = rowstart[node];
        const int end = rowstart[node + 1];
        float a0 = 0.f, a1 = 0.f, a2 = 0.f, a3 = 0.f;
        float a4 = 0.f, a5 = 0.f, a6 = 0.f, a7 = 0.f;
        float efacc = 0.f;
        int k = beg;
        while (k < end) {
            const int cnt = min(16, end - k);
            const int2 ep = elist[k + min(l, cnt - 1)];   // 16 records, 1 vec load
            int j = 0;
            for (; j + 8 <= cnt; j += 8) {
                uint4 v[8];
                float efv[8];
#pragma unroll
                for (int jj = 0; jj < 8; ++jj) {
                    const int s = __shfl(ep.x, j + jj, 16);
                    v[jj] = *(const uint4*)&h[((size_t)s << 7) + (l << 3)];
                    if (doEf) {
                        const int y = __shfl(ep.y, j + jj, 16);
                        efv[jj] = ef[((size_t)y << 4) + l];
                    }
                }
#pragma unroll
                for (int jj = 0; jj < 8; ++jj) {
                    a0 += b2f((ushort)(v[jj].x & 0xffff));
                    a1 += b2f((ushort)(v[jj].x >> 16));
                    a2 += b2f((ushort)(v[jj].y & 0xffff));
                    a3 += b2f((ushort)(v[jj].y >> 16));
                    a4 += b2f((ushort)(v[jj].z & 0xffff));
                    a5 += b2f((ushort)(v[jj].z >> 16));
                    a6 += b2f((ushort)(v[jj].w & 0xffff));
                    a7 += b2f((ushort)(v[jj].w >> 16));
                    if (doEf) efacc += efv[jj];
                }
            }
            for (; j < cnt; ++j) {
                const int s = __shfl(ep.x, j, 16);
                const uint4 v = *(const uint4*)&h[((size_t)s << 7) + (l << 3)];
                if (doEf) {
                    const int y = __shfl(ep.y, j, 16);
                    efacc += ef[((size_t)y << 4) + l];
                }
                a0 += b2f((ushort)(v.x & 0xffff));
                a1 += b2f((ushort)(v.x >> 16));
                a2 += b2f((ushort)(v.y & 0xffff));
                a3 += b2f((ushort)(v.y >> 16));
                a4 += b2f((ushort)(v.z & 0xffff));
                a5 += b2f((ushort)(v.z >> 16));
                a6 += b2f((ushort)(v.w & 0xffff));
                a7 += b2f((ushort)(v.w >> 16));
            }
            k += cnt;
        }
        uint4 o;
        o.x = pack2(a0, a1);
        o.y = pack2(a2, a3);
        o.z = pack2(a4, a5);
        o.w = pack2(a6, a7);
        *(uint4*)&agg[((size_t)node << 7) + (l << 3)] = o;
        if (doEf) aggef[((size_t)node << 4) + l] = f2b(efacc);
    }
}

// head: out[q] = z[a].topdot + z[b].botdot + lpb  (z = {za0,za1,zb0,zb1})
__launch_bounds__(256)
__global__ void head_kernel(const float4* __restrict__ z, const int* __restrict__ eli,
                            const float* __restrict__ lpb, float* __restrict__ out, int Q)
{
    const int q = blockIdx.x * 256 + threadIdx.x;
    if (q >= Q) return;
    const int a = eli[q];
    const int b = eli[Q + q];
    const float4 za = z[a];
    const float4 zb = z[b];
    float2 o = make_float2(za.x + zb.z + lpb[0], za.y + zb.w + lpb[1]);
    *(float2*)&out[(size_t)q * 2] = o;
}

extern "C" void kernel_launch(void* const* d_in, const int* in_sizes, int n_in,
                              void* d_out, int out_size, void* d_ws, size_t ws_size,
                              hipStream_t stream)
{
    const float* nf   = (const float*)d_in[0];
    const int*   ei   = (const int*)d_in[1];
    const float* ef   = (const float*)d_in[2];
    const int*   eli  = (const int*)d_in[3];
    const float* c1pW = (const float*)d_in[4];
    const float* c1pb = (const float*)d_in[5];
    const float* c1mW = (const float*)d_in[6];
    const float* c1mb = (const float*)d_in[7];
    const float* c2pW = (const float*)d_in[8];
    const float* c2pb = (const float*)d_in[9];
    const float* c2mW = (const float*)d_in[10];
    const float* c2mb = (const float*)d_in[11];
    const float* lpW  = (const float*)d_in[12];
    const float* lpb  = (const float*)d_in[13];
    float* out = (float*)d_out;

    const int N = in_sizes[0] / 128;
    const int E = in_sizes[1] / 2;
    const int Q = in_sizes[3] / 2;

    // ---- workspace layout ----
    float* DEG = (float*)d_ws;                 // N
    float* z   = DEG + N;                      // N*4 fp32 (head projections)
    int* counts    = (int*)(z + (size_t)N * 4);// N
    int* rowstart  = counts + N;               // N+1
    int* cursor    = rowstart + N + 1;         // N
    int* blocksums = cursor + N;               // 1024 pad
    uintptr_t ep8 = (uintptr_t)(blocksums + 1024);
    ep8 = (ep8 + 7) & ~(uintptr_t)7;
    int2* elist = (int2*)ep8;                  // E int2 (src, edge id)
    uintptr_t up = (uintptr_t)(elist + E);
    up = (up + 15) & ~(uintptr_t)15;
    ushort* h_bf   = (ushort*)up;              // N*128
    ushort* agg_bf = h_bf   + (size_t)N * 128; // N*128
    ushort* x1_bf  = agg_bf + (size_t)N * 128; // N*128
    ushort* ef_bf  = x1_bf  + (size_t)N * 128; // N*16
    ushort* wtp1   = ef_bf  + (size_t)N * 16;  // 128*128
    ushort* wtm1   = wtp1 + 128 * 128;         // 128*320
    ushort* wtp2   = wtm1 + 128 * 320;         // 128*128
    ushort* wtm2   = wtp2 + 128 * 128;         // 128*320

    const int gemmGrid = (N + 127) / 128;
    const int eGrid    = (E + 255) / 256;
    const int nGrid    = (N + 255) / 256;
    const int gGrid    = (N + 15) / 16;
    const int headGrid = (Q + 255) / 256;

    // ---- prep + CSR build ----
    prep<<<nGrid, 256, 0, stream>>>(c1pW, c2pW, c1mW, c2mW, wtp1, wtp2, wtm1, wtm2,
                                    counts, N);
    hist_kernel<<<eGrid, 256, 0, stream>>>(ei, counts, E);
    scan_phase1<<<nGrid, 256, 0, stream>>>(counts, rowstart, blocksums, N);
    scan_phase23<<<nGrid, 256, 0, stream>>>(counts, blocksums, rowstart, cursor, DEG, N, E);
    build_elist<<<eGrid, 256, 0, stream>>>(ei, cursor, elist, E);

    // ---- conv1 ----
    gemm_mfma<<<gemmGrid, 256, 0, stream>>>(nullptr, nullptr, nullptr, nf, DEG, wtp1,
                                            c1pb, h_bf, nullptr, nullptr, N, 128,
                                            F_RELU | F_OUTB | F_IN32);
    gather<<<gGrid, 256, 0, stream>>>(elist, rowstart, h_bf, agg_bf, ef, ef_bf, N, 1);
    gemm_mfma<<<gemmGrid, 256, 0, stream>>>(h_bf, agg_bf, ef_bf, nullptr, DEG, wtm1,
                                            c1mb, x1_bf, nullptr, nullptr, N, 320,
                                            F_MSG | F_RELU | F_DEGBIAS | F_OUTB);

    // ---- conv2 ----
    gemm_mfma<<<gemmGrid, 256, 0, stream>>>(x1_bf, nullptr, nullptr, nullptr, DEG, wtp2,
                                            c2pb, h_bf, nullptr, nullptr, N, 128,
                                            F_RELU | F_OUTB);
    gather<<<gGrid, 256, 0, stream>>>(elist, rowstart, h_bf, agg_bf, nullptr, nullptr, N, 0);
    gemm_mfma<<<gemmGrid, 256, 0, stream>>>(h_bf, agg_bf, ef_bf, nullptr, DEG, wtm2,
                                            c2mb, nullptr, lpW, z, N, 320,
                                            F_MSG | F_DEGBIAS | F_HEAD);

    // ---- head ----
    head_kernel<<<headGrid, 256, 0, stream>>>((const float4*)z, eli, lpb, out, Q);
}

// Round 2
// 291.808 us; speedup vs baseline: 1.1099x; 1.0853x over previous
//
#include <hip/hip_runtime.h>
#include <cstdint>
#include <cstddef>

// ---------------------------------------------------------------------------
// Net_25950192402497: 2-layer MLP-message GNN + link-prediction head.
// Identity: segment_sum(concat(x_i,x_j,ef)@W + b) over dst
//   = deg*(h@Wi + b) + (gather-sum h[src])@Wj + (gather-sum ef)@We
// R14: GEMM staging overhaul (budget says 5 GEMMs ~= 200us at ~6x their
// HBM floor -> staging-bound):
//  (a) hd = deg*relu(h) precomputed in pre-GEMM epilogue; ef zero-padded to
//      64 halfwords (efp) -> every MSG k-tile is a pure region copy.
//  (b) global_load_lds width=16 staging for xs and ws; m201-style chunk
//      swizzle (stored chunk = logical ^ (row&7)): inverse-swizzled per-lane
//      GLOBAL source + linear LDS dest + swizzled ds_read_b128 (rule #21).
//      Weights pre-blocked+pre-swizzled in prep -> contiguous ws source.
//  (c) LDS 36->32KB, launch_bounds (256,3) -> 3 blocks/CU.
// Gather kept at R13 form (16 lanes/node, uint4, unroll-8, shfl-broadcast).
// ---------------------------------------------------------------------------

typedef __attribute__((ext_vector_type(8))) short short8;
typedef __attribute__((ext_vector_type(4))) float float4v;

__device__ __forceinline__ ushort f2b(float f) {
    uint u = __float_as_uint(f);
    u = u + 0x7fff + ((u >> 16) & 1);          // round-to-nearest-even
    return (ushort)(u >> 16);
}
__device__ __forceinline__ float b2f(ushort h) {
    return __uint_as_float(((uint)h) << 16);
}
__device__ __forceinline__ uint pack2(float a, float b) {
    return (uint)f2b(a) | ((uint)f2b(b) << 16);
}

__device__ __forceinline__ void gload16(const void* gsrc, void* ldst) {
    __builtin_amdgcn_global_load_lds(
        (const __attribute__((address_space(1))) void*)gsrc,
        (__attribute__((address_space(3))) void*)ldst, 16, 0, 0);
}

#define F_MSG     1   // X = [hd | agg | efp] in k-space (Kp=320)
#define F_RELU    2
#define F_DEGBIAS 4
#define F_OUTB    8   // write bf16 output [row][128]
#define F_IN32    16  // A is fp32, convert during staging
#define F_HEAD    32  // no row output; emit z[row] = {za0,za1,zb0,zb1}

// MFMA GEMM: act( X[r,0:Kp] @ W[Kp,128] + bias ).
// Wt: blocked+pre-swizzled bf16 [tile][n=128][64] (see prep).
// Block: 128 rows x 128 cols, 4 waves; wave w owns rows w*32..w*32+31
// (2 m-subtiles of 16), all 128 cols as 8 col-tiles. acc = 2x8 float4.
// LDS: xs/ws linear [128][64] halfwords; chunk swizzle c^=(row&7) on 16B units.
__launch_bounds__(256, 3)
__global__ void gemm_mfma(const ushort* __restrict__ A, const ushort* __restrict__ B,
                          const ushort* __restrict__ EF, const float* __restrict__ A32,
                          const float* __restrict__ DEG, const ushort* __restrict__ Wt,
                          const float* __restrict__ bias, ushort* __restrict__ outB,
                          ushort* __restrict__ outD,
                          const float* __restrict__ lpW, float* __restrict__ z,
                          int M, int Kp, int flags)
{
    __shared__ ushort xs[128 * 64];   // 16 KB
    __shared__ ushort ws[128 * 64];   // 16 KB
    const int tid  = threadIdx.x;
    const int lane = tid & 63;
    const int wave = tid >> 6;
    const int row0 = blockIdx.x << 7;

    float4v acc[2][8];
#pragma unroll
    for (int m = 0; m < 2; ++m)
#pragma unroll
        for (int t = 0; t < 8; ++t) acc[m][t] = (float4v){0.f, 0.f, 0.f, 0.f};

    const int ar0   = (wave << 5) + (lane & 15);
    const int bcol  = lane & 15;
    const int cxor  = lane & 7;          // == (lds row)&7 for all fragment reads
    const int koffc = lane >> 4;         // logical chunk offset 0..3
    // per-lane swizzled source chunk offset for gload staging:
    // lds slot (lane&7) of row (..+lane>>3) holds logical chunk (lane&7)^(lane>>3)
    const int sw16  = (((lane & 7) ^ (lane >> 3)) << 4);

    for (int kt = 0; kt < Kp; kt += 64) {
        const int tix = kt >> 6;
        __syncthreads();
        // ---- ws stage: contiguous gload from blocked+pre-swizzled weights ----
#pragma unroll
        for (int i = 0; i < 4; ++i) {
            const int wsoff = (wave << 11) + (i << 9);           // halfword idx
            gload16((const char*)Wt + (((size_t)((tix << 13) + wsoff)) << 1) + (lane << 4),
                    &ws[wsoff]);
        }
        // ---- xs stage ----
        if (flags & F_IN32) {
            for (int idx = tid; idx < 128 * 8; idx += 256) {
                const int r  = idx >> 3;
                const int ch = idx & 7;
                const int gr = row0 + r;
                uint4 v = make_uint4(0, 0, 0, 0);
                if (gr < M) {
                    const float4 f0 = *(const float4*)&A32[((size_t)gr << 7) + kt + (ch << 3)];
                    const float4 f1 = *(const float4*)&A32[((size_t)gr << 7) + kt + (ch << 3) + 4];
                    v.x = pack2(f0.x, f0.y); v.y = pack2(f0.z, f0.w);
                    v.z = pack2(f1.x, f1.y); v.w = pack2(f1.z, f1.w);
                }
                *(uint4*)&xs[(r << 6) + ((ch ^ (r & 7)) << 3)] = v;
            }
        } else {
            const char* srcB; size_t strideB; int toffB;
            if (flags & F_MSG) {
                if (tix < 2)      { srcB = (const char*)A;  strideB = 256; toffB = (tix & 1) << 7; }
                else if (tix < 4) { srcB = (const char*)B;  strideB = 256; toffB = (tix & 1) << 7; }
                else              { srcB = (const char*)EF; strideB = 128; toffB = 0; }
            } else {
                srcB = (const char*)A; strideB = 256; toffB = (tix & 1) << 7;
            }
            const int rb = wave << 5;
#pragma unroll
            for (int i = 0; i < 4; ++i) {
                const int gr = min(row0 + rb + (i << 3) + (lane >> 3), M - 1);
                gload16(srcB + (size_t)gr * strideB + toffB + sw16,
                        &xs[(rb + (i << 3)) << 6]);
            }
        }
        __syncthreads();
        // ---- MFMA over the 64-k tile (2 chunk-groups of 32) ----
#pragma unroll
        for (int sc = 0; sc < 8; sc += 4) {
            const int ra = (sc + koffc) ^ cxor;   // stored slot index
            const short8 a0 = *(const short8*)&xs[(ar0 << 6) + (ra << 3)];
            const short8 a1 = *(const short8*)&xs[((ar0 + 16) << 6) + (ra << 3)];
#pragma unroll
            for (int t = 0; t < 8; ++t) {
                const short8 bf = *(const short8*)&ws[(((t << 4) + bcol) << 6) + (ra << 3)];
                acc[0][t] = __builtin_amdgcn_mfma_f32_16x16x32_bf16(a0, bf, acc[0][t], 0, 0, 0);
                acc[1][t] = __builtin_amdgcn_mfma_f32_16x16x32_bf16(a1, bf, acc[1][t], 0, 0, 0);
            }
        }
    }

    // ---- epilogue: C/D layout col=lane&15, row=(lane>>4)*4+reg ----
    float bcv[8];
#pragma unroll
    for (int t = 0; t < 8; ++t) bcv[t] = bias[(t << 4) + bcol];

    if (flags & F_HEAD) {
        const float2* lw = (const float2*)lpW;
        float2 wa[8], wb[8];
#pragma unroll
        for (int t = 0; t < 8; ++t) {
            const int col = (t << 4) + bcol;
            wa[t] = lw[col];
            wb[t] = lw[128 + col];
        }
#pragma unroll
        for (int m = 0; m < 2; ++m) {
            const int rbase = row0 + (wave << 5) + (m << 4) + ((lane >> 4) << 2);
#pragma unroll
            for (int r = 0; r < 4; ++r) {
                const int row = rbase + r;
                const float d = (row < M) ? DEG[row] : 0.f;
                float za0 = 0.f, za1 = 0.f, zb0 = 0.f, zb1 = 0.f;
#pragma unroll
                for (int t = 0; t < 8; ++t) {
                    const float v = acc[m][t][r] + d * bcv[t];
                    za0 += v * wa[t].x; za1 += v * wa[t].y;
                    zb0 += v * wb[t].x; zb1 += v * wb[t].y;
                }
#pragma unroll
                for (int mk = 8; mk > 0; mk >>= 1) {
                    za0 += __shfl_xor(za0, mk);
                    za1 += __shfl_xor(za1, mk);
                    zb0 += __shfl_xor(zb0, mk);
                    zb1 += __shfl_xor(zb1, mk);
                }
                if (bcol == 0 && row < M)
                    *(float4*)&z[(size_t)row * 4] = make_float4(za0, za1, zb0, zb1);
            }
        }
    } else {
#pragma unroll
        for (int m = 0; m < 2; ++m) {
            const int rbase = row0 + (wave << 5) + (m << 4) + ((lane >> 4) << 2);
#pragma unroll
            for (int r = 0; r < 4; ++r) {
                const int row = rbase + r;
                if (row >= M) continue;
                const float d = DEG[row];
#pragma unroll
                for (int t = 0; t < 8; ++t) {
                    const int col = (t << 4) + bcol;
                    float v = acc[m][t][r];
                    v += (flags & F_DEGBIAS) ? d * bcv[t] : bcv[t];
                    if (flags & F_RELU) v = fmaxf(v, 0.f);
                    outB[((size_t)row << 7) + col] = f2b(v);
                    if (outD) outD[((size_t)row << 7) + col] = f2b(v * d);
                }
            }
        }
    }
}

// ---- prep: zero counts + efp, build blocked+pre-swizzled bf16 weights ----
// Blocked layout: wblk[t][n][64], entry (t,n,s): stored chunk ch_st=s>>3 holds
// logical chunk ch = ch_st^(n&7): wblk[...] = W[t*64 + ch*8 + (s&7)][n].
__launch_bounds__(256)
__global__ void prep(const float* __restrict__ c1pW, const float* __restrict__ c2pW,
                     const float* __restrict__ c1mW, const float* __restrict__ c2mW,
                     ushort* __restrict__ wtp1, ushort* __restrict__ wtp2,
                     ushort* __restrict__ wtm1, ushort* __restrict__ wtm2,
                     ushort* __restrict__ efp, int* __restrict__ counts, int N)
{
    const int gtid = blockIdx.x * 256 + threadIdx.x;
    const int gstr = gridDim.x * 256;
    for (int i = gtid; i < N; i += gstr) counts[i] = 0;
    // zero efp: N rows x 64 halfwords = N*8 uint4
    for (int i = gtid; i < N * 8; i += gstr)
        ((uint4*)efp)[i] = make_uint4(0, 0, 0, 0);
    // pre weights: 2 tiles, Klim=128
    for (int idx = gtid; idx < 2 * 128 * 64; idx += gstr) {
        const int s = idx & 63, n = (idx >> 6) & 127, t = idx >> 13;
        const int k = t * 64 + (((s >> 3) ^ (n & 7)) << 3) + (s & 7);
        wtp1[idx] = f2b(c1pW[(size_t)k * 128 + n]);
        wtp2[idx] = f2b(c2pW[(size_t)k * 128 + n]);
    }
    // msg weights: 5 tiles, Klim=272
    for (int idx = gtid; idx < 5 * 128 * 64; idx += gstr) {
        const int s = idx & 63, n = (idx >> 6) & 127, t = idx >> 13;
        const int k = t * 64 + (((s >> 3) ^ (n & 7)) << 3) + (s & 7);
        wtm1[idx] = (k < 272) ? f2b(c1mW[(size_t)k * 128 + n]) : (ushort)0;
        wtm2[idx] = (k < 272) ? f2b(c2mW[(size_t)k * 128 + n]) : (ushort)0;
    }
}

__launch_bounds__(256)
__global__ void hist_kernel(const int* __restrict__ ei, int* __restrict__ counts, int E)
{
    const int e = blockIdx.x * 256 + threadIdx.x;
    if (e < E) atomicAdd(&counts[ei[E + e]], 1);
}

__launch_bounds__(256)
__global__ void scan_phase1(const int* __restrict__ counts, int* __restrict__ rowstart,
                            int* __restrict__ blocksums, int N)
{
    __shared__ int sdata[256];
    const int t = threadIdx.x;
    const int i = blockIdx.x * 256 + t;
    const int v = (i < N) ? counts[i] : 0;
    sdata[t] = v;
    __syncthreads();
    for (int off = 1; off < 256; off <<= 1) {
        const int add = (t >= off) ? sdata[t - off] : 0;
        __syncthreads();
        sdata[t] += add;
        __syncthreads();
    }
    if (i < N) rowstart[i] = sdata[t] - v;
    if (t == 255) blocksums[blockIdx.x] = sdata[255];
}

// merged scan phases 2+3: block vb sums blocksums[0..vb) itself (~196 blocks)
__launch_bounds__(256)
__global__ void scan_phase23(const int* __restrict__ counts, const int* __restrict__ bs,
                             int* __restrict__ rowstart, int* __restrict__ cursor,
                             float* __restrict__ degf, int N, int E)
{
    __shared__ int sdata[256];
    const int t = threadIdx.x;
    const int vb = blockIdx.x;
    int part = 0;
    for (int j = t; j < vb; j += 256) part += bs[j];
    sdata[t] = part;
    __syncthreads();
    for (int s = 128; s > 0; s >>= 1) {
        if (t < s) sdata[t] += sdata[t + s];
        __syncthreads();
    }
    const int off = sdata[0];
    const int i = vb * 256 + t;
    if (i < N) {
        const int rs = rowstart[i] + off;
        rowstart[i] = rs;
        cursor[i]   = rs;
        degf[i]     = (float)counts[i];
    }
    if (vb == 0 && t == 0) rowstart[N] = E;
}

__launch_bounds__(256)
__global__ void build_elist(const int* __restrict__ ei, int* __restrict__ cursor,
                            int2* __restrict__ elist, int E)
{
    const int e = blockIdx.x * 256 + threadIdx.x;
    if (e >= E) return;
    const int d = ei[E + e];
    const int pos = atomicAdd(&cursor[d], 1);
    elist[pos] = make_int2(ei[e], e);
}

// gather (R13): 16 lanes per node (4 nodes/wave), uint4 (16B) per lane per
// edge, unroll-8 -> 32 outstanding 256B row loads per wave. elist read once
// per 16-edge chunk as a lane-parallel int2 vector load; per-edge src /
// edge-id broadcast via __shfl. ef accumulation fused (writes efp [node][64]).
__launch_bounds__(256)
__global__ void gather(const int2* __restrict__ elist, const int* __restrict__ rowstart,
                       const ushort* __restrict__ h, ushort* __restrict__ agg,
                       const float* __restrict__ ef, ushort* __restrict__ aggef,
                       int N, int doEf)
{
    const int tid = threadIdx.x;
    const int grp = tid >> 4;          // 0..15 (node group within block)
    const int l   = tid & 15;          // lane within group
    const int nvb = (N + 15) / 16;     // 16 nodes per block
    for (int vb = blockIdx.x; vb < nvb; vb += gridDim.x) {
        const int node = vb * 16 + grp;
        if (node >= N) continue;
        const int beg = rowstart[node];
        const int end = rowstart[node + 1];
        float a0 = 0.f, a1 = 0.f, a2 = 0.f, a3 = 0.f;
        float a4 = 0.f, a5 = 0.f, a6 = 0.f, a7 = 0.f;
        float efacc = 0.f;
        int k = beg;
        while (k < end) {
            const int cnt = min(16, end - k);
            const int2 ep = elist[k + min(l, cnt - 1)];   // 16 records, 1 vec load
            int j = 0;
            for (; j + 8 <= cnt; j += 8) {
                uint4 v[8];
                float efv[8];
#pragma unroll
                for (int jj = 0; jj < 8; ++jj) {
                    const int s = __shfl(ep.x, j + jj, 16);
                    v[jj] = *(const uint4*)&h[((size_t)s << 7) + (l << 3)];
                    if (doEf) {
                        const int y = __shfl(ep.y, j + jj, 16);
                        efv[jj] = ef[((size_t)y << 4) + l];
                    }
                }
#pragma unroll
                for (int jj = 0; jj < 8; ++jj) {
                    a0 += b2f((ushort)(v[jj].x & 0xffff));
                    a1 += b2f((ushort)(v[jj].x >> 16));
                    a2 += b2f((ushort)(v[jj].y & 0xffff));
                    a3 += b2f((ushort)(v[jj].y >> 16));
                    a4 += b2f((ushort)(v[jj].z & 0xffff));
                    a5 += b2f((ushort)(v[jj].z >> 16));
                    a6 += b2f((ushort)(v[jj].w & 0xffff));
                    a7 += b2f((ushort)(v[jj].w >> 16));
                    if (doEf) efacc += efv[jj];
                }
            }
            for (; j < cnt; ++j) {
                const int s = __shfl(ep.x, j, 16);
                const uint4 v = *(const uint4*)&h[((size_t)s << 7) + (l << 3)];
                if (doEf) {
                    const int y = __shfl(ep.y, j, 16);
                    efacc += ef[((size_t)y << 4) + l];
                }
                a0 += b2f((ushort)(v.x & 0xffff));
                a1 += b2f((ushort)(v.x >> 16));
                a2 += b2f((ushort)(v.y & 0xffff));
                a3 += b2f((ushort)(v.y >> 16));
                a4 += b2f((ushort)(v.z & 0xffff));
                a5 += b2f((ushort)(v.z >> 16));
                a6 += b2f((ushort)(v.w & 0xffff));
                a7 += b2f((ushort)(v.w >> 16));
            }
            k += cnt;
        }
        uint4 o;
        o.x = pack2(a0, a1);
        o.y = pack2(a2, a3);
        o.z = pack2(a4, a5);
        o.w = pack2(a6, a7);
        *(uint4*)&agg[((size_t)node << 7) + (l << 3)] = o;
        if (doEf) aggef[((size_t)node << 6) + l] = f2b(efacc);
    }
}

// head: out[q] = z[a].topdot + z[b].botdot + lpb  (z = {za0,za1,zb0,zb1})
__launch_bounds__(256)
__global__ void head_kernel(const float4* __restrict__ z, const int* __restrict__ eli,
                            const float* __restrict__ lpb, float* __restrict__ out, int Q)
{
    const int q = blockIdx.x * 256 + threadIdx.x;
    if (q >= Q) return;
    const int a = eli[q];
    const int b = eli[Q + q];
    const float4 za = z[a];
    const float4 zb = z[b];
    float2 o = make_float2(za.x + zb.z + lpb[0], za.y + zb.w + lpb[1]);
    *(float2*)&out[(size_t)q * 2] = o;
}

extern "C" void kernel_launch(void* const* d_in, const int* in_sizes, int n_in,
                              void* d_out, int out_size, void* d_ws, size_t ws_size,
                              hipStream_t stream)
{
    const float* nf   = (const float*)d_in[0];
    const int*   ei   = (const int*)d_in[1];
    const float* ef   = (const float*)d_in[2];
    const int*   eli  = (const int*)d_in[3];
    const float* c1pW = (const float*)d_in[4];
    const float* c1pb = (const float*)d_in[5];
    const float* c1mW = (const float*)d_in[6];
    const float* c1mb = (const float*)d_in[7];
    const float* c2pW = (const float*)d_in[8];
    const float* c2pb = (const float*)d_in[9];
    const float* c2mW = (const float*)d_in[10];
    const float* c2mb = (const float*)d_in[11];
    const float* lpW  = (const float*)d_in[12];
    const float* lpb  = (const float*)d_in[13];
    float* out = (float*)d_out;

    const int N = in_sizes[0] / 128;
    const int E = in_sizes[1] / 2;
    const int Q = in_sizes[3] / 2;

    // ---- workspace layout ----
    float* DEG = (float*)d_ws;                 // N
    float* z   = DEG + N;                      // N*4 fp32 (head projections)
    int* counts    = (int*)(z + (size_t)N * 4);// N
    int* rowstart  = counts + N;               // N+1
    int* cursor    = rowstart + N + 1;         // N
    int* blocksums = cursor + N;               // 1024 pad
    uintptr_t ep8 = (uintptr_t)(blocksums + 1024);
    ep8 = (ep8 + 7) & ~(uintptr_t)7;
    int2* elist = (int2*)ep8;                  // E int2 (src, edge id)
    uintptr_t up = (uintptr_t)(elist + E);
    up = (up + 15) & ~(uintptr_t)15;
    ushort* h_bf   = (ushort*)up;              // N*128
    ushort* agg_bf = h_bf   + (size_t)N * 128; // N*128
    ushort* x1_bf  = agg_bf + (size_t)N * 128; // N*128
    ushort* hd_bf  = x1_bf  + (size_t)N * 128; // N*128 (deg-scaled h)
    ushort* efp    = hd_bf  + (size_t)N * 128; // N*64 (zero-padded ef sums)
    ushort* wtp1   = efp    + (size_t)N * 64;  // 2*128*64
    ushort* wtm1   = wtp1 + 2 * 128 * 64;      // 5*128*64
    ushort* wtp2   = wtm1 + 5 * 128 * 64;      // 2*128*64
    ushort* wtm2   = wtp2 + 2 * 128 * 64;      // 5*128*64

    const int gemmGrid = (N + 127) / 128;
    const int eGrid    = (E + 255) / 256;
    const int nGrid    = (N + 255) / 256;
    const int gGrid    = (N + 15) / 16;
    const int headGrid = (Q + 255) / 256;

    // ---- prep + CSR build ----
    prep<<<nGrid, 256, 0, stream>>>(c1pW, c2pW, c1mW, c2mW, wtp1, wtp2, wtm1, wtm2,
                                    efp, counts, N);
    hist_kernel<<<eGrid, 256, 0, stream>>>(ei, counts, E);
    scan_phase1<<<nGrid, 256, 0, stream>>>(counts, rowstart, blocksums, N);
    scan_phase23<<<nGrid, 256, 0, stream>>>(counts, blocksums, rowstart, cursor, DEG, N, E);
    build_elist<<<eGrid, 256, 0, stream>>>(ei, cursor, elist, E);

    // ---- conv1 ----
    gemm_mfma<<<gemmGrid, 256, 0, stream>>>(nullptr, nullptr, nullptr, nf, DEG, wtp1,
                                            c1pb, h_bf, hd_bf, nullptr, nullptr, N, 128,
                                            F_RELU | F_OUTB | F_IN32);
    gather<<<gGrid, 256, 0, stream>>>(elist, rowstart, h_bf, agg_bf, ef, efp, N, 1);
    gemm_mfma<<<gemmGrid, 256, 0, stream>>>(hd_bf, agg_bf, efp, nullptr, DEG, wtm1,
                                            c1mb, x1_bf, nullptr, nullptr, nullptr, N, 320,
                                            F_MSG | F_RELU | F_DEGBIAS | F_OUTB);

    // ---- conv2 ----
    gemm_mfma<<<gemmGrid, 256, 0, stream>>>(x1_bf, nullptr, nullptr, nullptr, DEG, wtp2,
                                            c2pb, h_bf, hd_bf, nullptr, nullptr, N, 128,
                                            F_RELU | F_OUTB);
    gather<<<gGrid, 256, 0, stream>>>(elist, rowstart, h_bf, agg_bf, nullptr, nullptr, N, 0);
    gemm_mfma<<<gemmGrid, 256, 0, stream>>>(hd_bf, agg_bf, efp, nullptr, DEG, wtm2,
                                            c2mb, nullptr, nullptr, lpW, z, N, 320,
                                            F_MSG | F_DEGBIAS | F_HEAD);

    // ---- head ----
    head_kernel<<<headGrid, 256, 0, stream>>>((const float4*)z, eli, lpb, out, Q);
}

// Round 3
// 286.154 us; speedup vs baseline: 1.1318x; 1.0198x over previous
//
#include <hip/hip_runtime.h>
#include <cstdint>
#include <cstddef>

// ---------------------------------------------------------------------------
// Net_25950192402497: 2-layer MLP-message GNN + link-prediction head.
// Identity: segment_sum(concat(x_i,x_j,ef)@W + b) over dst
//   = deg*(h@Wi + b) + (gather-sum h[src])@Wj + (gather-sum ef)@We
// R15:
//  (a) nf converted to bf16 in prep -> conv1-pre uses the pure gload path;
//      F_IN32 VGPR-staging path deleted.
//  (b) conv1-msg + conv2-pre FUSED (gemm_msg_pre): stage1 Kp=320 MSG GEMM ->
//      x1 tile kept in LDS (bf16, XOR-swizzled A-layout, 32KB) -> stage2
//      K=128 GEMM vs W2p. x1 never touches global (saves 25.6MB + 1 launch).
//  (c) gather: serial tail removed -- predicated batches of 8 (clamped src,
//      zeroed contribution); mean deg=10 now fully rides the 32-rows-in-
//      flight MLP path.
// ---------------------------------------------------------------------------

typedef __attribute__((ext_vector_type(8))) short short8;
typedef __attribute__((ext_vector_type(4))) float float4v;

__device__ __forceinline__ ushort f2b(float f) {
    uint u = __float_as_uint(f);
    u = u + 0x7fff + ((u >> 16) & 1);          // round-to-nearest-even
    return (ushort)(u >> 16);
}
__device__ __forceinline__ float b2f(ushort h) {
    return __uint_as_float(((uint)h) << 16);
}
__device__ __forceinline__ uint pack2(float a, float b) {
    return (uint)f2b(a) | ((uint)f2b(b) << 16);
}

__device__ __forceinline__ void gload16(const void* gsrc, void* ldst) {
    __builtin_amdgcn_global_load_lds(
        (const __attribute__((address_space(1))) void*)gsrc,
        (__attribute__((address_space(3))) void*)ldst, 16, 0, 0);
}

#define F_MSG     1   // X = [hd | agg | efp] in k-space (Kp=320)
#define F_RELU    2
#define F_DEGBIAS 4
#define F_OUTB    8   // write bf16 output [row][128]
#define F_HEAD    32  // no row output; emit z[row] = {za0,za1,zb0,zb1}

// MFMA GEMM: act( X[r,0:Kp] @ W[Kp,128] + bias ).
// Wt: blocked+pre-swizzled bf16 [tile][n=128][64] (see prep).
// Block: 128 rows x 128 cols, 4 waves; wave w owns rows w*32..w*32+31.
// LDS xs/ws linear [128][64] halfwords; chunk swizzle ch^=(row&7) on 16B units.
__launch_bounds__(256, 3)
__global__ void gemm_mfma(const ushort* __restrict__ A, const ushort* __restrict__ B,
                          const ushort* __restrict__ EF,
                          const float* __restrict__ DEG, const ushort* __restrict__ Wt,
                          const float* __restrict__ bias, ushort* __restrict__ outB,
                          ushort* __restrict__ outD,
                          const float* __restrict__ lpW, float* __restrict__ z,
                          int M, int Kp, int flags)
{
    __shared__ ushort xs[128 * 64];   // 16 KB
    __shared__ ushort ws[128 * 64];   // 16 KB
    const int tid  = threadIdx.x;
    const int lane = tid & 63;
    const int wave = tid >> 6;
    const int row0 = blockIdx.x << 7;

    float4v acc[2][8];
#pragma unroll
    for (int m = 0; m < 2; ++m)
#pragma unroll
        for (int t = 0; t < 8; ++t) acc[m][t] = (float4v){0.f, 0.f, 0.f, 0.f};

    const int ar0   = (wave << 5) + (lane & 15);
    const int bcol  = lane & 15;
    const int cxor  = lane & 7;
    const int koffc = lane >> 4;
    const int sw16  = (((lane & 7) ^ (lane >> 3)) << 4);

    for (int kt = 0; kt < Kp; kt += 64) {
        const int tix = kt >> 6;
        __syncthreads();
        // ---- ws stage ----
#pragma unroll
        for (int i = 0; i < 4; ++i) {
            const int wsoff = (wave << 11) + (i << 9);
            gload16((const char*)Wt + (((size_t)((tix << 13) + wsoff)) << 1) + (lane << 4),
                    &ws[wsoff]);
        }
        // ---- xs stage ----
        {
            const char* srcB; size_t strideB; int toffB;
            if (flags & F_MSG) {
                if (tix < 2)      { srcB = (const char*)A;  strideB = 256; toffB = (tix & 1) << 7; }
                else if (tix < 4) { srcB = (const char*)B;  strideB = 256; toffB = (tix & 1) << 7; }
                else              { srcB = (const char*)EF; strideB = 128; toffB = 0; }
            } else {
                srcB = (const char*)A; strideB = 256; toffB = (tix & 1) << 7;
            }
            const int rb = wave << 5;
#pragma unroll
            for (int i = 0; i < 4; ++i) {
                const int gr = min(row0 + rb + (i << 3) + (lane >> 3), M - 1);
                gload16(srcB + (size_t)gr * strideB + toffB + sw16,
                        &xs[(rb + (i << 3)) << 6]);
            }
        }
        __syncthreads();
#pragma unroll
        for (int sc = 0; sc < 8; sc += 4) {
            const int ra = (sc + koffc) ^ cxor;
            const short8 a0 = *(const short8*)&xs[(ar0 << 6) + (ra << 3)];
            const short8 a1 = *(const short8*)&xs[((ar0 + 16) << 6) + (ra << 3)];
#pragma unroll
            for (int t = 0; t < 8; ++t) {
                const short8 bf = *(const short8*)&ws[(((t << 4) + bcol) << 6) + (ra << 3)];
                acc[0][t] = __builtin_amdgcn_mfma_f32_16x16x32_bf16(a0, bf, acc[0][t], 0, 0, 0);
                acc[1][t] = __builtin_amdgcn_mfma_f32_16x16x32_bf16(a1, bf, acc[1][t], 0, 0, 0);
            }
        }
    }

    // ---- epilogue: C/D layout col=lane&15, row=(lane>>4)*4+reg ----
    float bcv[8];
#pragma unroll
    for (int t = 0; t < 8; ++t) bcv[t] = bias[(t << 4) + bcol];

    if (flags & F_HEAD) {
        const float2* lw = (const float2*)lpW;
        float2 wa[8], wb[8];
#pragma unroll
        for (int t = 0; t < 8; ++t) {
            const int col = (t << 4) + bcol;
            wa[t] = lw[col];
            wb[t] = lw[128 + col];
        }
#pragma unroll
        for (int m = 0; m < 2; ++m) {
            const int rbase = row0 + (wave << 5) + (m << 4) + ((lane >> 4) << 2);
#pragma unroll
            for (int r = 0; r < 4; ++r) {
                const int row = rbase + r;
                const float d = (row < M) ? DEG[row] : 0.f;
                float za0 = 0.f, za1 = 0.f, zb0 = 0.f, zb1 = 0.f;
#pragma unroll
                for (int t = 0; t < 8; ++t) {
                    const float v = acc[m][t][r] + d * bcv[t];
                    za0 += v * wa[t].x; za1 += v * wa[t].y;
                    zb0 += v * wb[t].x; zb1 += v * wb[t].y;
                }
#pragma unroll
                for (int mk = 8; mk > 0; mk >>= 1) {
                    za0 += __shfl_xor(za0, mk);
                    za1 += __shfl_xor(za1, mk);
                    zb0 += __shfl_xor(zb0, mk);
                    zb1 += __shfl_xor(zb1, mk);
                }
                if (bcol == 0 && row < M)
                    *(float4*)&z[(size_t)row * 4] = make_float4(za0, za1, zb0, zb1);
            }
        }
    } else {
#pragma unroll
        for (int m = 0; m < 2; ++m) {
            const int rbase = row0 + (wave << 5) + (m << 4) + ((lane >> 4) << 2);
#pragma unroll
            for (int r = 0; r < 4; ++r) {
                const int row = rbase + r;
                if (row >= M) continue;
                const float d = DEG[row];
#pragma unroll
                for (int t = 0; t < 8; ++t) {
                    const int col = (t << 4) + bcol;
                    float v = acc[m][t][r];
                    v += (flags & F_DEGBIAS) ? d * bcv[t] : bcv[t];
                    if (flags & F_RELU) v = fmaxf(v, 0.f);
                    outB[((size_t)row << 7) + col] = f2b(v);
                    if (outD) outD[((size_t)row << 7) + col] = f2b(v * d);
                }
            }
        }
    }
}

// ---------------------------------------------------------------------------
// Fused conv1-msg + conv2-pre:
//   stage1: x1 = relu([HD|AGG|EFP] @ Wm + deg*bm)   (Kp=320, per-block tile)
//   stage2: h2 = relu(x1 @ Wp + bp); outH = h2, outHD = deg*h2
// x1 tile (128x128 bf16) lives only in LDS, stored in swizzled A-layout:
//   halfword idx = row*128 + ((ch&8)|((ch^row)&7))*8 + (col&7), ch = col>>3.
// ---------------------------------------------------------------------------
__launch_bounds__(256, 3)
__global__ void gemm_msg_pre(const ushort* __restrict__ HD, const ushort* __restrict__ AGG,
                             const ushort* __restrict__ EFP, const float* __restrict__ DEG,
                             const ushort* __restrict__ Wm, const float* __restrict__ bm,
                             const ushort* __restrict__ Wp, const float* __restrict__ bp,
                             ushort* __restrict__ outH, ushort* __restrict__ outHD, int M)
{
    __shared__ ushort smem[128 * 128 + 128 * 64];   // 48 KB: x2 tile + ws
    ushort* x2 = smem;             // [128][128] swizzled (stage1 xs uses first 16KB)
    ushort* ws = smem + 128 * 128; // [128][64]

    const int tid  = threadIdx.x;
    const int lane = tid & 63;
    const int wave = tid >> 6;
    const int row0 = blockIdx.x << 7;

    float4v acc[2][8];
#pragma unroll
    for (int m = 0; m < 2; ++m)
#pragma unroll
        for (int t = 0; t < 8; ++t) acc[m][t] = (float4v){0.f, 0.f, 0.f, 0.f};

    const int ar0   = (wave << 5) + (lane & 15);
    const int bcol  = lane & 15;
    const int cxor  = lane & 7;
    const int koffc = lane >> 4;
    const int sw16  = (((lane & 7) ^ (lane >> 3)) << 4);

    // ---- stage 1: Kp=320 over [HD | AGG | EFP] ----
    for (int kt = 0; kt < 320; kt += 64) {
        const int tix = kt >> 6;
        __syncthreads();
#pragma unroll
        for (int i = 0; i < 4; ++i) {
            const int wsoff = (wave << 11) + (i << 9);
            gload16((const char*)Wm + (((size_t)((tix << 13) + wsoff)) << 1) + (lane << 4),
                    &ws[wsoff]);
        }
        {
            const char* srcB; size_t strideB; int toffB;
            if (tix < 2)      { srcB = (const char*)HD;  strideB = 256; toffB = (tix & 1) << 7; }
            else if (tix < 4) { srcB = (const char*)AGG; strideB = 256; toffB = (tix & 1) << 7; }
            else              { srcB = (const char*)EFP; strideB = 128; toffB = 0; }
            const int rb = wave << 5;
#pragma unroll
            for (int i = 0; i < 4; ++i) {
                const int gr = min(row0 + rb + (i << 3) + (lane >> 3), M - 1);
                gload16(srcB + (size_t)gr * strideB + toffB + sw16,
                        &smem[(rb + (i << 3)) << 6]);
            }
        }
        __syncthreads();
#pragma unroll
        for (int sc = 0; sc < 8; sc += 4) {
            const int ra = (sc + koffc) ^ cxor;
            const short8 a0 = *(const short8*)&smem[(ar0 << 6) + (ra << 3)];
            const short8 a1 = *(const short8*)&smem[((ar0 + 16) << 6) + (ra << 3)];
#pragma unroll
            for (int t = 0; t < 8; ++t) {
                const short8 bf = *(const short8*)&ws[(((t << 4) + bcol) << 6) + (ra << 3)];
                acc[0][t] = __builtin_amdgcn_mfma_f32_16x16x32_bf16(a0, bf, acc[0][t], 0, 0, 0);
                acc[1][t] = __builtin_amdgcn_mfma_f32_16x16x32_bf16(a1, bf, acc[1][t], 0, 0, 0);
            }
        }
    }

    // ---- epilogue 1: x1 = relu(acc + deg*bm) -> x2 (LDS, swizzled) ----
    float bcv1[8];
#pragma unroll
    for (int t = 0; t < 8; ++t) bcv1[t] = bm[(t << 4) + bcol];

    __syncthreads();   // all stage-1 LDS reads complete before overwrite
#pragma unroll
    for (int m = 0; m < 2; ++m) {
        const int rl0 = (wave << 5) + (m << 4) + ((lane >> 4) << 2);
#pragma unroll
        for (int r = 0; r < 4; ++r) {
            const int rl  = rl0 + r;
            const int row = row0 + rl;
            const float d = (row < M) ? DEG[row] : 0.f;
#pragma unroll
            for (int t = 0; t < 8; ++t) {
                const int col = (t << 4) + bcol;
                const float v = fmaxf(acc[m][t][r] + d * bcv1[t], 0.f);
                const int ch = col >> 3;
                const int st = (ch & 8) | ((ch ^ rl) & 7);
                x2[(rl << 7) + (st << 3) + (col & 7)] = f2b(v);
            }
        }
    }

#pragma unroll
    for (int m = 0; m < 2; ++m)
#pragma unroll
        for (int t = 0; t < 8; ++t) acc[m][t] = (float4v){0.f, 0.f, 0.f, 0.f};

    // ---- stage 2: h2 = relu(x1 @ Wp + bp), K=128 ----
    for (int kt2 = 0; kt2 < 2; ++kt2) {
        __syncthreads();   // x2 writes visible (kt2=0) / ws reads done (kt2=1)
#pragma unroll
        for (int i = 0; i < 4; ++i) {
            const int wsoff = (wave << 11) + (i << 9);
            gload16((const char*)Wp + (((size_t)((kt2 << 13) + wsoff)) << 1) + (lane << 4),
                    &ws[wsoff]);
        }
        __syncthreads();
#pragma unroll
        for (int sc = 0; sc < 8; sc += 4) {
            const int ra = (sc + koffc) ^ cxor;
            const short8 a0 = *(const short8*)&x2[(ar0 << 7) + (kt2 << 6) + (ra << 3)];
            const short8 a1 = *(const short8*)&x2[((ar0 + 16) << 7) + (kt2 << 6) + (ra << 3)];
#pragma unroll
            for (int t = 0; t < 8; ++t) {
                const short8 bf = *(const short8*)&ws[(((t << 4) + bcol) << 6) + (ra << 3)];
                acc[0][t] = __builtin_amdgcn_mfma_f32_16x16x32_bf16(a0, bf, acc[0][t], 0, 0, 0);
                acc[1][t] = __builtin_amdgcn_mfma_f32_16x16x32_bf16(a1, bf, acc[1][t], 0, 0, 0);
            }
        }
    }

    // ---- epilogue 2: outH = relu(acc + bp), outHD = deg*outH ----
    float bcv2[8];
#pragma unroll
    for (int t = 0; t < 8; ++t) bcv2[t] = bp[(t << 4) + bcol];
#pragma unroll
    for (int m = 0; m < 2; ++m) {
        const int rbase = row0 + (wave << 5) + (m << 4) + ((lane >> 4) << 2);
#pragma unroll
        for (int r = 0; r < 4; ++r) {
            const int row = rbase + r;
            if (row >= M) continue;
            const float d = DEG[row];
#pragma unroll
            for (int t = 0; t < 8; ++t) {
                const int col = (t << 4) + bcol;
                const float v = fmaxf(acc[m][t][r] + bcv2[t], 0.f);
                outH[((size_t)row << 7) + col]  = f2b(v);
                outHD[((size_t)row << 7) + col] = f2b(v * d);
            }
        }
    }
}

// ---- prep: zero counts + efp, nf->bf16, blocked+pre-swizzled weights ----
__launch_bounds__(256)
__global__ void prep(const float* __restrict__ nf, ushort* __restrict__ nf_bf,
                     const float* __restrict__ c1pW, const float* __restrict__ c2pW,
                     const float* __restrict__ c1mW, const float* __restrict__ c2mW,
                     ushort* __restrict__ wtp1, ushort* __restrict__ wtp2,
                     ushort* __restrict__ wtm1, ushort* __restrict__ wtm2,
                     ushort* __restrict__ efp, int* __restrict__ counts, int N)
{
    const int gtid = blockIdx.x * 256 + threadIdx.x;
    const int gstr = gridDim.x * 256;
    for (int i = gtid; i < N; i += gstr) counts[i] = 0;
    // nf -> bf16 (8 floats -> one uint4 per iteration)
    for (int i = gtid; i < N * 16; i += gstr) {
        const float4 f0 = *(const float4*)&nf[(size_t)i * 8];
        const float4 f1 = *(const float4*)&nf[(size_t)i * 8 + 4];
        uint4 v;
        v.x = pack2(f0.x, f0.y); v.y = pack2(f0.z, f0.w);
        v.z = pack2(f1.x, f1.y); v.w = pack2(f1.z, f1.w);
        ((uint4*)nf_bf)[i] = v;
    }
    // zero efp: N rows x 64 halfwords = N*8 uint4
    for (int i = gtid; i < N * 8; i += gstr)
        ((uint4*)efp)[i] = make_uint4(0, 0, 0, 0);
    // pre weights: 2 tiles each
    for (int idx = gtid; idx < 2 * 128 * 64; idx += gstr) {
        const int s = idx & 63, n = (idx >> 6) & 127, t = idx >> 13;
        const int k = t * 64 + (((s >> 3) ^ (n & 7)) << 3) + (s & 7);
        wtp1[idx] = f2b(c1pW[(size_t)k * 128 + n]);
        wtp2[idx] = f2b(c2pW[(size_t)k * 128 + n]);
    }
    // msg weights: 5 tiles, Klim=272
    for (int idx = gtid; idx < 5 * 128 * 64; idx += gstr) {
        const int s = idx & 63, n = (idx >> 6) & 127, t = idx >> 13;
        const int k = t * 64 + (((s >> 3) ^ (n & 7)) << 3) + (s & 7);
        wtm1[idx] = (k < 272) ? f2b(c1mW[(size_t)k * 128 + n]) : (ushort)0;
        wtm2[idx] = (k < 272) ? f2b(c2mW[(size_t)k * 128 + n]) : (ushort)0;
    }
}

__launch_bounds__(256)
__global__ void hist_kernel(const int* __restrict__ ei, int* __restrict__ counts, int E)
{
    const int e = blockIdx.x * 256 + threadIdx.x;
    if (e < E) atomicAdd(&counts[ei[E + e]], 1);
}

__launch_bounds__(256)
__global__ void scan_phase1(const int* __restrict__ counts, int* __restrict__ rowstart,
                            int* __restrict__ blocksums, int N)
{
    __shared__ int sdata[256];
    const int t = threadIdx.x;
    const int i = blockIdx.x * 256 + t;
    const int v = (i < N) ? counts[i] : 0;
    sdata[t] = v;
    __syncthreads();
    for (int off = 1; off < 256; off <<= 1) {
        const int add = (t >= off) ? sdata[t - off] : 0;
        __syncthreads();
        sdata[t] += add;
        __syncthreads();
    }
    if (i < N) rowstart[i] = sdata[t] - v;
    if (t == 255) blocksums[blockIdx.x] = sdata[255];
}

// merged scan phases 2+3: block vb sums blocksums[0..vb) itself (~196 blocks)
__launch_bounds__(256)
__global__ void scan_phase23(const int* __restrict__ counts, const int* __restrict__ bs,
                             int* __restrict__ rowstart, int* __restrict__ cursor,
                             float* __restrict__ degf, int N, int E)
{
    __shared__ int sdata[256];
    const int t = threadIdx.x;
    const int vb = blockIdx.x;
    int part = 0;
    for (int j = t; j < vb; j += 256) part += bs[j];
    sdata[t] = part;
    __syncthreads();
    for (int s = 128; s > 0; s >>= 1) {
        if (t < s) sdata[t] += sdata[t + s];
        __syncthreads();
    }
    const int off = sdata[0];
    const int i = vb * 256 + t;
    if (i < N) {
        const int rs = rowstart[i] + off;
        rowstart[i] = rs;
        cursor[i]   = rs;
        degf[i]     = (float)counts[i];
    }
    if (vb == 0 && t == 0) rowstart[N] = E;
}

__launch_bounds__(256)
__global__ void build_elist(const int* __restrict__ ei, int* __restrict__ cursor,
                            int2* __restrict__ elist, int E)
{
    const int e = blockIdx.x * 256 + threadIdx.x;
    if (e >= E) return;
    const int d = ei[E + e];
    const int pos = atomicAdd(&cursor[d], 1);
    elist[pos] = make_int2(ei[e], e);
}

// gather (R15): 16 lanes/node (4 nodes/wave), uint4/lane/edge, fully
// predicated batches of 8 (clamped src index, zeroed contribution) -> no
// serial tail; every edge rides the 32-rows-in-flight path. elist read once
// per 16-edge chunk + __shfl broadcast. ef fused (writes efp [node][64]).
__launch_bounds__(256)
__global__ void gather(const int2* __restrict__ elist, const int* __restrict__ rowstart,
                       const ushort* __restrict__ h, ushort* __restrict__ agg,
                       const float* __restrict__ ef, ushort* __restrict__ aggef,
                       int N, int doEf)
{
    const int tid = threadIdx.x;
    const int grp = tid >> 4;          // 0..15 (node group within block)
    const int l   = tid & 15;          // lane within group
    const int nvb = (N + 15) / 16;     // 16 nodes per block
    for (int vb = blockIdx.x; vb < nvb; vb += gridDim.x) {
        const int node = vb * 16 + grp;
        if (node >= N) continue;
        const int beg = rowstart[node];
        const int end = rowstart[node + 1];
        float a0 = 0.f, a1 = 0.f, a2 = 0.f, a3 = 0.f;
        float a4 = 0.f, a5 = 0.f, a6 = 0.f, a7 = 0.f;
        float efacc = 0.f;
        for (int k = beg; k < end; k += 16) {
            const int cnt = min(16, end - k);
            const int2 ep = elist[k + min(l, cnt - 1)];   // 16 records, 1 vec load
            for (int j = 0; j < cnt; j += 8) {
                uint4 v[8];
                float efv[8];
#pragma unroll
                for (int jj = 0; jj < 8; ++jj) {
                    const int idx = min(j + jj, cnt - 1);
                    const int s = __shfl(ep.x, idx, 16);
                    v[jj] = *(const uint4*)&h[((size_t)s << 7) + (l << 3)];
                    if (doEf) {
                        const int y = __shfl(ep.y, idx, 16);
                        efv[jj] = ef[((size_t)y << 4) + l];
                    }
                }
#pragma unroll
                for (int jj = 0; jj < 8; ++jj) {
                    if (j + jj >= cnt) {
                        v[jj] = make_uint4(0, 0, 0, 0);
                        efv[jj] = 0.f;
                    }
                    a0 += b2f((ushort)(v[jj].x & 0xffff));
                    a1 += b2f((ushort)(v[jj].x >> 16));
                    a2 += b2f((ushort)(v[jj].y & 0xffff));
                    a3 += b2f((ushort)(v[jj].y >> 16));
                    a4 += b2f((ushort)(v[jj].z & 0xffff));
                    a5 += b2f((ushort)(v[jj].z >> 16));
                    a6 += b2f((ushort)(v[jj].w & 0xffff));
                    a7 += b2f((ushort)(v[jj].w >> 16));
                    if (doEf) efacc += efv[jj];
                }
            }
        }
        uint4 o;
        o.x = pack2(a0, a1);
        o.y = pack2(a2, a3);
        o.z = pack2(a4, a5);
        o.w = pack2(a6, a7);
        *(uint4*)&agg[((size_t)node << 7) + (l << 3)] = o;
        if (doEf) aggef[((size_t)node << 6) + l] = f2b(efacc);
    }
}

// head: out[q] = z[a].topdot + z[b].botdot + lpb  (z = {za0,za1,zb0,zb1})
__launch_bounds__(256)
__global__ void head_kernel(const float4* __restrict__ z, const int* __restrict__ eli,
                            const float* __restrict__ lpb, float* __restrict__ out, int Q)
{
    const int q = blockIdx.x * 256 + threadIdx.x;
    if (q >= Q) return;
    const int a = eli[q];
    const int b = eli[Q + q];
    const float4 za = z[a];
    const float4 zb = z[b];
    float2 o = make_float2(za.x + zb.z + lpb[0], za.y + zb.w + lpb[1]);
    *(float2*)&out[(size_t)q * 2] = o;
}

extern "C" void kernel_launch(void* const* d_in, const int* in_sizes, int n_in,
                              void* d_out, int out_size, void* d_ws, size_t ws_size,
                              hipStream_t stream)
{
    const float* nf   = (const float*)d_in[0];
    const int*   ei   = (const int*)d_in[1];
    const float* ef   = (const float*)d_in[2];
    const int*   eli  = (const int*)d_in[3];
    const float* c1pW = (const float*)d_in[4];
    const float* c1pb = (const float*)d_in[5];
    const float* c1mW = (const float*)d_in[6];
    const float* c1mb = (const float*)d_in[7];
    const float* c2pW = (const float*)d_in[8];
    const float* c2pb = (const float*)d_in[9];
    const float* c2mW = (const float*)d_in[10];
    const float* c2mb = (const float*)d_in[11];
    const float* lpW  = (const float*)d_in[12];
    const float* lpb  = (const float*)d_in[13];
    float* out = (float*)d_out;

    const int N = in_sizes[0] / 128;
    const int E = in_sizes[1] / 2;
    const int Q = in_sizes[3] / 2;

    // ---- workspace layout ----
    float* DEG = (float*)d_ws;                 // N
    float* z   = DEG + N;                      // N*4 fp32 (head projections)
    int* counts    = (int*)(z + (size_t)N * 4);// N
    int* rowstart  = counts + N;               // N+1
    int* cursor    = rowstart + N + 1;         // N
    int* blocksums = cursor + N;               // 1024 pad
    uintptr_t ep8 = (uintptr_t)(blocksums + 1024);
    ep8 = (ep8 + 7) & ~(uintptr_t)7;
    int2* elist = (int2*)ep8;                  // E int2 (src, edge id)
    uintptr_t up = (uintptr_t)(elist + E);
    up = (up + 15) & ~(uintptr_t)15;
    ushort* nf_bf  = (ushort*)up;              // N*128
    ushort* h_bf   = nf_bf  + (size_t)N * 128; // N*128
    ushort* agg_bf = h_bf   + (size_t)N * 128; // N*128
    ushort* hd_bf  = agg_bf + (size_t)N * 128; // N*128 (deg-scaled h)
    ushort* efp    = hd_bf  + (size_t)N * 128; // N*64 (zero-padded ef sums)
    ushort* wtp1   = efp    + (size_t)N * 64;  // 2*128*64
    ushort* wtm1   = wtp1 + 2 * 128 * 64;      // 5*128*64
    ushort* wtp2   = wtm1 + 5 * 128 * 64;      // 2*128*64
    ushort* wtm2   = wtp2 + 2 * 128 * 64;      // 5*128*64

    const int gemmGrid = (N + 127) / 128;
    const int eGrid    = (E + 255) / 256;
    const int nGrid    = (N + 255) / 256;
    const int gGrid    = (N + 15) / 16;
    const int headGrid = (Q + 255) / 256;

    // ---- prep + CSR build ----
    prep<<<nGrid, 256, 0, stream>>>(nf, nf_bf, c1pW, c2pW, c1mW, c2mW,
                                    wtp1, wtp2, wtm1, wtm2, efp, counts, N);
    hist_kernel<<<eGrid, 256, 0, stream>>>(ei, counts, E);
    scan_phase1<<<nGrid, 256, 0, stream>>>(counts, rowstart, blocksums, N);
    scan_phase23<<<nGrid, 256, 0, stream>>>(counts, blocksums, rowstart, cursor, DEG, N, E);
    build_elist<<<eGrid, 256, 0, stream>>>(ei, cursor, elist, E);

    // ---- conv1 ----
    gemm_mfma<<<gemmGrid, 256, 0, stream>>>(nf_bf, nullptr, nullptr, DEG, wtp1,
                                            c1pb, h_bf, hd_bf, nullptr, nullptr, N, 128,
                                            F_RELU | F_OUTB);
    gather<<<gGrid, 256, 0, stream>>>(elist, rowstart, h_bf, agg_bf, ef, efp, N, 1);

    // ---- conv1-msg + conv2-pre (fused) ----
    gemm_msg_pre<<<gemmGrid, 256, 0, stream>>>(hd_bf, agg_bf, efp, DEG, wtm1, c1mb,
                                               wtp2, c2pb, h_bf, hd_bf, N);

    // ---- conv2 ----
    gather<<<gGrid, 256, 0, stream>>>(elist, rowstart, h_bf, agg_bf, nullptr, nullptr, N, 0);
    gemm_mfma<<<gemmGrid, 256, 0, stream>>>(hd_bf, agg_bf, efp, DEG, wtm2,
                                            c2mb, nullptr, nullptr, lpW, z, N, 320,
                                            F_MSG | F_DEGBIAS | F_HEAD);

    // ---- head ----
    head_kernel<<<headGrid, 256, 0, stream>>>((const float4*)z, eli, lpb, out, Q);
}